// Round 21
// baseline (447.773 us; speedup 1.0000x reference)
//
#include <hip/hip_runtime.h>

typedef __attribute__((ext_vector_type(4))) float f32x4;
typedef __attribute__((ext_vector_type(8))) short bf16x8;
typedef __attribute__((ext_vector_type(8))) unsigned short u16x8;
typedef unsigned short u16;

#define HID 780
#define NH 10
#define FO 78

__device__ inline u16 f2b(float f) {  // fp32 -> bf16 RNE
  unsigned u = __float_as_uint(f);
  unsigned r = (u + 0x7fff + ((u >> 16) & 1)) >> 16;
  return (u16)r;
}
__device__ inline float b2f(u16 b) { return __uint_as_float(((unsigned)b) << 16); }

__device__ inline void gld16(const u16* g, u16* l) {
  __builtin_amdgcn_global_load_lds(
      (const __attribute__((address_space(1))) unsigned int*)g,
      (__attribute__((address_space(3))) unsigned int*)l, 16, 0, 0);
}

__device__ inline int swz_bid() {
  int gx = gridDim.x, gy = gridDim.y, gz = gridDim.z;
  int nwg = gx * gy * gz;
  int bid = (blockIdx.z * gy + blockIdx.y) * gx + blockIdx.x;
  if ((nwg & 7) == 0) bid = (bid & 7) * (nwg >> 3) + (bid >> 3);
  return bid;
}

// ---------------- shared GEMM core (bf16 C), 2-phase pipelined, chunk-swizzled LDS ----
// LDS tile row = 4 x 16B chunks; stage fetches global chunk c^(r&3) into linear
// dest chunk c (involution); reads use chunk lk^(lr&3). Banks: 8-way -> 4-way.
__device__ __forceinline__ void gemm_core(const u16* __restrict__ A,
    const u16* __restrict__ BT, u16* __restrict__ C, float* __restrict__ att_out,
    int Ncols, int KP, int ldc, int bx, int by,
    u16 (*As)[4096], u16 (*Bs)[4096])
{
  const int tid = threadIdx.x;
  const int row0 = by << 7, col0 = bx << 7;
  const int l = tid & 63, wid = tid >> 6;
  const int wr = wid >> 1, wc = wid & 1;
  const int lr = l & 15, lk = l >> 4;
  const int lkx = (lk ^ (lr & 3)) << 3;          // swizzled read chunk offset (u16)
  const int c0 = (wid << 6) + l, c1 = 256 + c0;
  const int sw0 = ((c0 & 3) ^ ((c0 >> 2) & 3)) << 3;   // swizzled source chunk (u16)
  const int sw1 = ((c1 & 3) ^ ((c1 >> 2) & 3)) << 3;
  const u16* gA0 = A + (size_t)(row0 + (c0 >> 2)) * KP + sw0;
  const u16* gA1 = A + (size_t)(row0 + (c1 >> 2)) * KP + sw1;
  const u16* gB0 = BT + (size_t)(col0 + (c0 >> 2)) * KP + sw0;
  const u16* gB1 = BT + (size_t)(col0 + (c1 >> 2)) * KP + sw1;
  const int d0 = (wid << 6) << 3, d1 = (256 + (wid << 6)) << 3;

  f32x4 acc[4][4];
#pragma unroll
  for (int i = 0; i < 4; ++i)
#pragma unroll
    for (int j = 0; j < 4; ++j) acc[i][j] = (f32x4){0.f, 0.f, 0.f, 0.f};

  gld16(gA0, &As[0][d0]); gld16(gA1, &As[0][d1]);
  gld16(gB0, &Bs[0][d0]); gld16(gB1, &Bs[0][d1]);
  __syncthreads();

  int cur = 0;
  for (int k0 = 0; k0 < KP; k0 += 32) {
    if (k0 + 32 < KP) {
      int nx = cur ^ 1, kn = k0 + 32;
      gld16(gA0 + kn, &As[nx][d0]); gld16(gA1 + kn, &As[nx][d1]);
      gld16(gB0 + kn, &Bs[nx][d0]); gld16(gB1 + kn, &Bs[nx][d1]);
    }
    const u16* Ac = As[cur];
    const u16* Bc = Bs[cur];
    bf16x8 af[4], bfr[4];
#pragma unroll
    for (int fm = 0; fm < 4; ++fm)
      af[fm] = *(const bf16x8*)&Ac[((wr * 64 + fm * 16 + lr) << 5) + lkx];
#pragma unroll
    for (int fn = 0; fn < 4; ++fn)
      bfr[fn] = *(const bf16x8*)&Bc[((wc * 64 + fn * 16 + lr) << 5) + lkx];
#pragma unroll
    for (int fm = 0; fm < 4; ++fm)
#pragma unroll
      for (int fn = 0; fn < 4; ++fn)
        acc[fm][fn] = __builtin_amdgcn_mfma_f32_16x16x32_bf16(af[fm], bfr[fn], acc[fm][fn], 0, 0, 0);
    __syncthreads();
    cur ^= 1;
  }
#pragma unroll
  for (int fm = 0; fm < 4; ++fm)
#pragma unroll
    for (int fn = 0; fn < 4; ++fn) {
      int col = col0 + wc * 64 + fn * 16 + lr;
      f32x4 v = acc[fm][fn];
      int rbase = row0 + wr * 64 + fm * 16 + lk * 4;
      if (col < Ncols) {
#pragma unroll
        for (int j = 0; j < 4; ++j)
          C[(size_t)(rbase + j) * ldc + col] = f2b(v[j]);
      } else {
        if (att_out != nullptr && col < Ncols + 20) {
          int c = col - Ncols;
#pragma unroll
          for (int j = 0; j < 4; ++j)
            att_out[(size_t)(rbase + j) * 20 + c] = v[j];
        }
        if (col < ldc) {
#pragma unroll
          for (int j = 0; j < 4; ++j) C[(size_t)(rbase + j) * ldc + col] = 0;
        }
      }
    }
}

__global__ __launch_bounds__(256) void gemm_mfma(const u16* __restrict__ A,
    const u16* __restrict__ BT, u16* __restrict__ C, float* __restrict__ att_out,
    int Ncols, int KP, int ldc)
{
  __shared__ u16 As[2][4096];
  __shared__ u16 Bs[2][4096];
  int t = swz_bid();
  gemm_core(A, BT, C, att_out, Ncols, KP, ldc, t % gridDim.x, t / gridDim.x, As, Bs);
}

__global__ __launch_bounds__(256) void gemm_dual(
    const u16* __restrict__ A1, const u16* __restrict__ B1, u16* __restrict__ C1,
    float* __restrict__ att1, int N1, int K1, int l1, int gx1, int nb1,
    const u16* __restrict__ A2, const u16* __restrict__ B2, u16* __restrict__ C2,
    int N2, int K2, int l2, int gx2)
{
  __shared__ u16 As[2][4096];
  __shared__ u16 Bs[2][4096];
  int bi = blockIdx.x;
  if (bi < nb1) {
    int t = bi;
    if ((nb1 & 7) == 0) t = (bi & 7) * (nb1 >> 3) + (bi >> 3);
    gemm_core(A1, B1, C1, att1, N1, K1, l1, t % gx1, t / gx1, As, Bs);
  } else {
    int nb2 = gridDim.x - nb1, b2 = bi - nb1;
    int t = b2;
    if ((nb2 & 7) == 0) t = (b2 & 7) * (nb2 >> 3) + (b2 >> 3);
    gemm_core(A2, B2, C2, nullptr, N2, K2, l2, t % gx2, t / gx2, As, Bs);
  }
}

// ---------------- split-K core: fp32 atomic partials, 2-phase, swizzled ----------------
__device__ __forceinline__ void sk_core(const u16* __restrict__ A,
    const u16* __restrict__ BT, float* __restrict__ C,
    int Ncols, int KP, int kchunk, int bx, int by, int bz,
    u16 (*As)[4096], u16 (*Bs)[4096])
{
  const int tid = threadIdx.x;
  const int row0 = by << 7, col0 = bx << 7;
  const int kbeg = bz * kchunk;
  const int kend = min(KP, kbeg + kchunk);
  const int l = tid & 63, wid = tid >> 6;
  const int wr = wid >> 1, wc = wid & 1;
  const int lr = l & 15, lk = l >> 4;
  const int lkx = (lk ^ (lr & 3)) << 3;
  const int c0 = (wid << 6) + l, c1 = 256 + c0;
  const int sw0 = ((c0 & 3) ^ ((c0 >> 2) & 3)) << 3;
  const int sw1 = ((c1 & 3) ^ ((c1 >> 2) & 3)) << 3;
  const u16* gA0 = A + (size_t)(row0 + (c0 >> 2)) * KP + sw0 + kbeg;
  const u16* gA1 = A + (size_t)(row0 + (c1 >> 2)) * KP + sw1 + kbeg;
  const u16* gB0 = BT + (size_t)(col0 + (c0 >> 2)) * KP + sw0 + kbeg;
  const u16* gB1 = BT + (size_t)(col0 + (c1 >> 2)) * KP + sw1 + kbeg;
  const int d0 = (wid << 6) << 3, d1 = (256 + (wid << 6)) << 3;

  f32x4 acc[4][4];
#pragma unroll
  for (int i = 0; i < 4; ++i)
#pragma unroll
    for (int j = 0; j < 4; ++j) acc[i][j] = (f32x4){0.f, 0.f, 0.f, 0.f};

  gld16(gA0, &As[0][d0]); gld16(gA1, &As[0][d1]);
  gld16(gB0, &Bs[0][d0]); gld16(gB1, &Bs[0][d1]);
  __syncthreads();

  int cur = 0;
  for (int k0 = kbeg; k0 < kend; k0 += 32) {
    if (k0 + 32 < kend) {
      int nx = cur ^ 1, kn = k0 + 32 - kbeg;
      gld16(gA0 + kn, &As[nx][d0]); gld16(gA1 + kn, &As[nx][d1]);
      gld16(gB0 + kn, &Bs[nx][d0]); gld16(gB1 + kn, &Bs[nx][d1]);
    }
    const u16* Ac = As[cur];
    const u16* Bc = Bs[cur];
    bf16x8 af[4], bfr[4];
#pragma unroll
    for (int fm = 0; fm < 4; ++fm)
      af[fm] = *(const bf16x8*)&Ac[((wr * 64 + fm * 16 + lr) << 5) + lkx];
#pragma unroll
    for (int fn = 0; fn < 4; ++fn)
      bfr[fn] = *(const bf16x8*)&Bc[((wc * 64 + fn * 16 + lr) << 5) + lkx];
#pragma unroll
    for (int fm = 0; fm < 4; ++fm)
#pragma unroll
      for (int fn = 0; fn < 4; ++fn)
        acc[fm][fn] = __builtin_amdgcn_mfma_f32_16x16x32_bf16(af[fm], bfr[fn], acc[fm][fn], 0, 0, 0);
    __syncthreads();
    cur ^= 1;
  }
#pragma unroll
  for (int fm = 0; fm < 4; ++fm)
#pragma unroll
    for (int fn = 0; fn < 4; ++fn) {
      int col = col0 + wc * 64 + fn * 16 + lr;
      if (col < Ncols) {
        f32x4 v = acc[fm][fn];
        int rbase = row0 + wr * 64 + fm * 16 + lk * 4;
#pragma unroll
        for (int j = 0; j < 4; ++j)
          atomicAdd(&C[(size_t)(rbase + j) * Ncols + col], v[j]);
      }
    }
}

__global__ __launch_bounds__(256) void gemm_sk(const u16* __restrict__ A,
    const u16* __restrict__ BT, float* __restrict__ C,
    int Ncols, int KP, int kchunk)
{
  __shared__ u16 As[2][4096];
  __shared__ u16 Bs[2][4096];
  int t = swz_bid();
  int bx = t % gridDim.x;
  int by = (t / gridDim.x) % gridDim.y;
  int bz = t / (gridDim.x * gridDim.y);
  sk_core(A, BT, C, Ncols, KP, kchunk, bx, by, bz, As, Bs);
}

__global__ __launch_bounds__(256) void gemm_sk_dual(
    const u16* __restrict__ A1, const u16* __restrict__ B1, float* __restrict__ C1,
    int N1, int K1, int kc1, int gx1, int gy1, int nb1,
    const u16* __restrict__ A2, const u16* __restrict__ B2, float* __restrict__ C2,
    int N2, int K2, int kc2, int gx2, int gy2)
{
  __shared__ u16 As[2][4096];
  __shared__ u16 Bs[2][4096];
  int bi = blockIdx.x;
  if (bi < nb1) {
    int t = bi;
    if ((nb1 & 7) == 0) t = (bi & 7) * (nb1 >> 3) + (bi >> 3);
    sk_core(A1, B1, C1, N1, K1, kc1, t % gx1, (t / gx1) % gy1, t / (gx1 * gy1), As, Bs);
  } else {
    int nb2 = gridDim.x - nb1, b2 = bi - nb1;
    int t = b2;
    if ((nb2 & 7) == 0) t = (b2 & 7) * (nb2 >> 3) + (b2 >> 3);
    sk_core(A2, B2, C2, N2, K2, kc2, t % gx2, (t / gx2) % gy2, t / (gx2 * gy2), As, Bs);
  }
}

// fp32 compact [M][N] -> bf16 [M][ldco] with bias/relu, zero-pad cols [N,padTo)
template<bool RELU>
__global__ void bias_act_pad(const float* __restrict__ Cf,
    const float* __restrict__ bias, u16* __restrict__ out,
    int M, int N, int padTo, int ldco)
{
  int idx = blockIdx.x * 256 + threadIdx.x;
  if (idx >= M * padTo) return;
  int r = idx / padTo, c = idx - r * padTo;
  if (c < N) {
    float v = Cf[(size_t)r * N + c] + bias[c];
    if (RELU) v = v > 0.f ? v : 0.f;
    out[(size_t)r * ldco + c] = f2b(v);
  } else {
    out[(size_t)r * ldco + c] = 0;
  }
}

__global__ void bias_dual(const float* __restrict__ C1, const float* __restrict__ b1,
    u16* __restrict__ o1, int M1, int N1, int p1, int l1,
    const float* __restrict__ C2, const float* __restrict__ b2,
    u16* __restrict__ o2, int M2, int N2, int p2, int l2)
{
  int idx = blockIdx.x * 256 + threadIdx.x;
  int t1 = M1 * p1;
  if (idx < t1) {
    int r = idx / p1, c = idx - r * p1;
    if (c < N1) o1[(size_t)r * l1 + c] = f2b(C1[(size_t)r * N1 + c] + b1[c]);
    else o1[(size_t)r * l1 + c] = 0;
    return;
  }
  idx -= t1;
  if (idx >= M2 * p2) return;
  int r = idx / p2, c = idx - r * p2;
  if (c < N2) {
    float v = C2[(size_t)r * N2 + c] + b2[c];
    v = v > 0.f ? v : 0.f;
    o2[(size_t)r * l2 + c] = f2b(v);
  } else {
    o2[(size_t)r * l2 + c] = 0;
  }
}

// ---------------- fused prep ----------------
__device__ inline void wtile(const float* __restrict__ W, u16* __restrict__ WT,
    int K, int Ncol, int KP, int NP, int bx, int by, int skip_lo, int skip_hi,
    u16 (*tbuf)[33])
{
  int tn0 = bx << 5, tk0 = by << 5;
  int lx = threadIdx.x & 31, ly = threadIdx.x >> 5;
#pragma unroll
  for (int r = 0; r < 32; r += 8) {
    int k = tk0 + ly + r, n = tn0 + lx;
    tbuf[ly + r][lx] = (k < K && n < Ncol) ? f2b(W[(size_t)k * Ncol + n]) : (u16)0;
  }
  __syncthreads();
#pragma unroll
  for (int r = 0; r < 32; r += 8) {
    int n = tn0 + ly + r, k = tk0 + lx;
    if (n < NP && k < KP && !(n >= skip_lo && n < skip_hi))
      WT[(size_t)n * KP + k] = tbuf[lx][ly + r];
  }
}

__global__ __launch_bounds__(256) void prep_all(
    const float* __restrict__ x, u16* __restrict__ xb,
    const float* __restrict__ gat_W, u16* __restrict__ wt1,
    const float* __restrict__ gcn_W, u16* __restrict__ wt2,
    const float* __restrict__ fcg1_W, u16* __restrict__ wtg1,
    const float* __restrict__ fcg2_W, u16* __restrict__ wtg2,
    const float* __restrict__ fc1xt_W, u16* __restrict__ wtxt,
    const float* __restrict__ fc1_W, u16* __restrict__ wtf1,
    const float* __restrict__ fc2_W, u16* __restrict__ wtf2,
    const float* __restrict__ convW, u16* __restrict__ wtc,
    const float* __restrict__ asv, const float* __restrict__ adv,
    const int* __restrict__ tgt, u16* __restrict__ Ind,
    const int* __restrict__ ei, int* __restrict__ cnt, int N, int E)
{
  __shared__ u16 tbuf[32][33];
  __shared__ unsigned char tl[1000];
  int bi = blockIdx.x, tid = threadIdx.x;
  const int s0 = (N * 96 + 255) / 256;
  if (bi < s0) {
    int idx = bi * 256 + tid;
    if (idx < N * 96) {
      int r = idx / 96, c = idx - r * 96;
      xb[idx] = (c < FO) ? f2b(x[(size_t)r * FO + c]) : (u16)0;
    }
    return;
  }
  bi -= s0;
  if (bi < 84)   { wtile(gat_W,  wt1,  FO,   HID,  96,   896,  bi % 28, bi / 28, 780, 800, tbuf); return; }
  bi -= 84;
  if (bi < 700)  { wtile(gcn_W,  wt2,  HID,  HID,  800,  896,  bi % 28, bi / 28, 1 << 30, 0, tbuf); return; }
  bi -= 700;
  if (bi < 2352) { wtile(fcg1_W, wtg1, 1560, 1500, 1568, 1536, bi % 48, bi / 48, 1 << 30, 0, tbuf); return; }
  bi -= 2352;
  if (bi < 188)  { wtile(fcg2_W, wtg2, 1500, 128,  1504, 128,  bi % 4,  bi / 4,  1 << 30, 0, tbuf); return; }
  bi -= 188;
  if (bi < 484)  { wtile(fc1xt_W, wtxt, 3872, 128, 3872, 128,  bi % 4,  bi / 4,  1 << 30, 0, tbuf); return; }
  bi -= 484;
  if (bi < 256)  { wtile(fc1_W,  wtf1, 256,  1024, 256,  1024, bi % 32, bi / 32, 1 << 30, 0, tbuf); return; }
  bi -= 256;
  if (bi < 512)  { wtile(fc2_W,  wtf2, 1024, 512,  1024, 512,  bi % 16, bi / 16, 1 << 30, 0, tbuf); return; }
  bi -= 512;
  if (bi < 1024) {
    int idx = bi * 256 + tid;
    int ok = idx >> 10, c = idx & 1023;
    int o = ok >> 3, k = ok & 7;
    wtc[idx] = (c < 1000) ? f2b(convW[(size_t)o * 8000 + c * 8 + k]) : (u16)0;
    return;
  }
  bi -= 1024;
  if (bi < 20) {
    int j = bi, k = tid;
    if (k >= 96) return;
    float s = 0.f;
    if (k < FO) {
      int h = (j < 10) ? j : j - 10;
      const float* av = ((j < 10) ? asv : adv) + h * FO;
      const float* wr = gat_W + (size_t)k * HID + h * FO;
      for (int f = 0; f < FO; ++f) s += wr[f] * av[f];
    }
    wt1[(size_t)(HID + j) * 96 + k] = f2b(s);
    return;
  }
  bi -= 20;
  if (bi < 1024) {
    int b = bi;
    for (int i = tid; i < 1000; i += 256) tl[i] = (unsigned char)tgt[b * 1000 + i];
    __syncthreads();
    u16* out = Ind + (size_t)b * 26 * 1024;
    for (int ci = tid; ci < 26 * 128; ci += 256) {
      int v = ci >> 7, c0 = (ci & 127) << 3;
      u16x8 w;
#pragma unroll
      for (int j = 0; j < 8; ++j) {
        int c = c0 + j;
        w[j] = (c < 1000 && tl[c] == v) ? (u16)0x3F80 : (u16)0;
      }
      *(u16x8*)(out + v * 1024 + c0) = w;
    }
    return;
  }
  bi -= 1024;
  {
    int e = bi * 256 + tid;
    if (e >= E + N) return;
    int dst = (e < E) ? ei[E + e] : (e - E);
    atomicAdd(&cnt[dst], 1);
  }
}

// ---------------- multi-block scan ----------------
__global__ __launch_bounds__(1024) void scan1(const int* __restrict__ cnt,
    int* __restrict__ offs, float* __restrict__ dinv, int* __restrict__ bsum, int N)
{
  __shared__ int sc[1024];
  int b = blockIdx.x, tid = threadIdx.x;
  int g = b * 1024 + tid;
  int c = (g < N) ? cnt[g] : 0;
  sc[tid] = c;
  __syncthreads();
  for (int off = 1; off < 1024; off <<= 1) {
    int v = sc[tid];
    int add = (tid >= off) ? sc[tid - off] : 0;
    __syncthreads();
    sc[tid] = v + add;
    __syncthreads();
  }
  if (g < N) {
    offs[g] = sc[tid] - c;
    dinv[g] = c > 0 ? rsqrtf((float)c) : 0.f;
  }
  if (tid == 1023) bsum[b] = sc[1023];
}

__global__ __launch_bounds__(1024) void scan2(int* __restrict__ offs,
    const int* __restrict__ bsum, int N, int nblk)
{
  int b = blockIdx.x, tid = threadIdx.x;
  int base = 0;
  for (int j = 0; j < b; ++j) base += bsum[j];
  int g = b * 1024 + tid;
  if (g < N && b > 0) offs[g] += base;
  if (b == nblk - 1 && tid == 1023) offs[N] = base + bsum[b];
}

__global__ void fill_csr(const int* __restrict__ ei, int E, int N,
    const int* __restrict__ offs, int* __restrict__ fillpos, int* __restrict__ csr_src)
{
  int e = blockIdx.x * 256 + threadIdx.x;
  if (e >= E + N) return;
  int src, dst;
  if (e < E) { src = ei[e]; dst = ei[E + e]; }
  else { src = e - E; dst = e - E; }
  int p = offs[dst] + atomicAdd(&fillpos[dst], 1);
  csr_src[p] = src;
}

// ---------------- GAT gather ----------------
#define CH 48
__global__ __launch_bounds__(64) void gat_gather(const u16* __restrict__ h,
    const float* __restrict__ att,
    const int* __restrict__ offs, const int* __restrict__ csr_src,
    const float* __restrict__ gat_bias, u16* __restrict__ x1b)
{
  int n = blockIdx.x, lane = threadIdx.x;
  int o0 = offs[n], deg = offs[n + 1] - o0;
  __shared__ float ad[NH], ssum[NH];
  __shared__ float wbuf[CH][NH];
  __shared__ int slist[CH];
  if (lane < NH) { ad[lane] = att[n * 20 + 10 + lane]; ssum[lane] = 0.f; }
  const int s0 = lane, s1 = 64 + lane;
  const bool a1 = s1 < 100;
  int hA0 = min((s0 * 8) / FO, NH - 1), bb0 = FO * ((s0 * 8) / FO + 1) - s0 * 8;
  int hB0 = min((s0 * 8) / FO + 1, NH - 1);
  int hA1 = min((s1 * 8) / FO, NH - 1), bb1 = FO * ((s1 * 8) / FO + 1) - s1 * 8;
  int hB1 = min((s1 * 8) / FO + 1, NH - 1);
  float acc0[8], acc1[8];
#pragma unroll
  for (int j = 0; j < 8; ++j) { acc0[j] = 0.f; acc1[j] = 0.f; }
  __syncthreads();

  for (int e0 = 0; e0 < deg; e0 += CH) {
    int ce = min(CH, deg - e0);
    for (int idx = lane; idx < ce * NH; idx += 64) {
      int e = idx / NH, hd = idx - e * NH;
      int s = csr_src[o0 + e0 + e];
      float l = att[s * 20 + hd] + ad[hd];
      l = l > 0.f ? l : 0.2f * l;
      float w = __expf(l);
      wbuf[e][hd] = w;
      atomicAdd(&ssum[hd], w);
    }
    for (int idx = lane; idx < ce; idx += 64) slist[idx] = csr_src[o0 + e0 + idx];
    __syncthreads();
    for (int e = 0; e < ce; ++e) {
      const u16* hs = h + (size_t)slist[e] * 800;
      u16x8 v0 = *(const u16x8*)(hs + s0 * 8);
      float wA0 = wbuf[e][hA0], wB0 = wbuf[e][hB0];
#pragma unroll
      for (int j = 0; j < 8; ++j)
        acc0[j] += (j < bb0 ? wA0 : wB0) * b2f(v0[j]);
      if (a1) {
        u16x8 v1 = *(const u16x8*)(hs + s1 * 8);
        float wA1 = wbuf[e][hA1], wB1 = wbuf[e][hB1];
#pragma unroll
        for (int j = 0; j < 8; ++j)
          acc1[j] += (j < bb1 ? wA1 : wB1) * b2f(v1[j]);
      }
    }
    __syncthreads();
  }
  float iA0 = 1.f / (ssum[hA0] + 1e-16f), iB0 = 1.f / (ssum[hB0] + 1e-16f);
  u16x8 o0v;
#pragma unroll
  for (int j = 0; j < 8; ++j) {
    int f = s0 * 8 + j;
    float v = acc0[j] * (j < bb0 ? iA0 : iB0) + gat_bias[f];
    o0v[j] = f2b(v > 0.f ? v : 0.f);
  }
  *(u16x8*)(x1b + (size_t)n * 800 + s0 * 8) = o0v;
  if (a1) {
    float iA1 = 1.f / (ssum[hA1] + 1e-16f), iB1 = 1.f / (ssum[hB1] + 1e-16f);
    u16x8 o1v;
#pragma unroll
    for (int j = 0; j < 8; ++j) {
      int f = s1 * 8 + j;
      if (f < HID) {
        float v = acc1[j] * (j < bb1 ? iA1 : iB1) + gat_bias[f];
        o1v[j] = f2b(v > 0.f ? v : 0.f);
      } else o1v[j] = 0;
    }
    *(u16x8*)(x1b + (size_t)n * 800 + s1 * 8) = o1v;
  }
}

// ---------------- GCN gather + per-graph pooling: shfl-staged edges ----------------
__global__ __launch_bounds__(256) void gcn_pool(const u16* __restrict__ h2,
    const int* __restrict__ offs, const int* __restrict__ csr_src,
    const float* __restrict__ dinv, const float* __restrict__ gcn_bias,
    const int* __restrict__ batch, int N, u16* __restrict__ gb)
{
  int gi = blockIdx.x, tid = threadIdx.x;
  int grp = tid >> 6, lane = tid & 63;
  __shared__ int se[2];
  __shared__ float smx[HID];
  __shared__ float ssm[HID];
  for (int f = tid; f < HID; f += 256) { smx[f] = 0.f; ssm[f] = 0.f; }
  if (tid < 2) {
    int target = gi + tid;
    int lo = 0, hi = N;
    while (lo < hi) { int mid = (lo + hi) >> 1; if (batch[mid] < target) lo = mid + 1; else hi = mid; }
    se[tid] = lo;
  }
  __syncthreads();
  int s = se[0], e = se[1];
  const int s0 = lane, s1 = 64 + lane;
  const bool a1 = s1 < 100;
  float bv0[8], bv1[8];
#pragma unroll
  for (int j = 0; j < 8; ++j) {
    int f0 = s0 * 8 + j, f1 = s1 * 8 + j;
    bv0[j] = gcn_bias[f0];
    bv1[j] = (a1 && f1 < HID) ? gcn_bias[f1] : 0.f;
  }
  float mx0[8], sm0[8], mx1[8], sm1[8];
#pragma unroll
  for (int j = 0; j < 8; ++j) { mx0[j] = 0.f; sm0[j] = 0.f; mx1[j] = 0.f; sm1[j] = 0.f; }

  for (int n = s + grp; n < e; n += 4) {
    int o0 = offs[n], deg = offs[n + 1] - o0;
    float dn = dinv[n];
    float acc0[8], acc1[8];
#pragma unroll
    for (int j = 0; j < 8; ++j) { acc0[j] = 0.f; acc1[j] = 0.f; }
    for (int eb = 0; eb < deg; eb += 64) {
      int ce = min(64, deg - eb);
      int   src_l = (lane < ce) ? csr_src[o0 + eb + lane] : 0;
      float c_l   = (lane < ce) ? dn * dinv[src_l] : 0.f;
      int   sc = __shfl(src_l, 0, 64);
      float cc = __shfl(c_l, 0, 64);
      const u16* hr = h2 + (size_t)sc * 800;
      u16x8 v0 = *(const u16x8*)(hr + s0 * 8);
      u16x8 v1 = a1 ? *(const u16x8*)(hr + s1 * 8) : v0;
      for (int ed = 0; ed < ce; ++ed) {
        u16x8 n0 = v0, n1 = v1;
        float nc = 0.f;
        if (ed + 1 < ce) {
          int ns = __shfl(src_l, ed + 1, 64);
          nc = __shfl(c_l, ed + 1, 64);
          const u16* nh = h2 + (size_t)ns * 800;
          n0 = *(const u16x8*)(nh + s0 * 8);
          if (a1) n1 = *(const u16x8*)(nh + s1 * 8);
        }
#pragma unroll
        for (int j = 0; j < 8; ++j) acc0[j] += cc * b2f(v0[j]);
        if (a1) {
#pragma unroll
          for (int j = 0; j < 8; ++j) acc1[j] += cc * b2f(v1[j]);
        }
        v0 = n0; v1 = n1; cc = nc;
      }
    }
#pragma unroll
    for (int j = 0; j < 8; ++j) {
      float v = acc0[j] + bv0[j];
      v = v > 0.f ? v : 0.f;
      mx0[j] = fmaxf(mx0[j], v); sm0[j] += v;
      float w = acc1[j] + bv1[j];
      w = w > 0.f ? w : 0.f;
      mx1[j] = fmaxf(mx1[j], w); sm1[j] += w;
    }
  }
#pragma unroll
  for (int j = 0; j < 8; ++j) {
    int f0 = s0 * 8 + j;
    atomicMax((unsigned*)&smx[f0], __float_as_uint(mx0[j]));
    atomicAdd(&ssm[f0], sm0[j]);
    int f1 = s1 * 8 + j;
    if (a1 && f1 < HID) {
      atomicMax((unsigned*)&smx[f1], __float_as_uint(mx1[j]));
      atomicAdd(&ssm[f1], sm1[j]);
    }
  }
  __syncthreads();
  float inv = 1.f / fmaxf((float)(e - s), 1.f);
  for (int f = tid; f < HID; f += 256) {
    gb[(size_t)gi * 1568 + f] = f2b(smx[f]);
    gb[(size_t)gi * 1568 + HID + f] = f2b(ssm[f] * inv);
  }
  if (tid < 8) gb[(size_t)gi * 1568 + 1560 + tid] = 0;
}

// ---------------- conv from bf16 A ----------------
__global__ __launch_bounds__(256) void conv_xt(const u16* __restrict__ Aall,
    const float* __restrict__ embed, const float* __restrict__ cbias,
    u16* __restrict__ out)
{
  int b = blockIdx.x, tid = threadIdx.x;
  __shared__ __align__(16) float Al[6656];
  __shared__ __align__(16) float el[3360];
  const u16* Ab = Aall + (size_t)b * 6656;
  for (int i = tid; i < 6656; i += 256) Al[i] = b2f(Ab[i]);
  for (int i = tid; i < 3328; i += 256) el[i] = embed[i];
  if (tid < 32) el[3328 + tid] = 0.f;
  __syncthreads();
  for (int grp = tid; grp < 512; grp += 256) {
    int o = grp >> 4;
    int l0 = (grp & 15) << 3;
    float cb = cbias[o];
    float acc[8];
#pragma unroll
    for (int j = 0; j < 8; ++j) acc[j] = cb;
    for (int v = 0; v < 26; ++v) {
      const float* ap = &Al[v * 256 + (o << 3)];
      f32x4 a0 = *(const f32x4*)ap;
      f32x4 a1 = *(const f32x4*)(ap + 4);
      const float* ep = &el[v * 128 + l0];
      f32x4 e0 = *(const f32x4*)ep;
      f32x4 e1 = *(const f32x4*)(ep + 4);
      f32x4 e2 = *(const f32x4*)(ep + 8);
      f32x4 e3 = *(const f32x4*)(ep + 12);
      float a[8] = { a0[0], a0[1], a0[2], a0[3], a1[0], a1[1], a1[2], a1[3] };
      float e[16] = { e0[0], e0[1], e0[2], e0[3], e1[0], e1[1], e1[2], e1[3],
                      e2[0], e2[1], e2[2], e2[3], e3[0], e3[1], e3[2], e3[3] };
#pragma unroll
      for (int k = 0; k < 8; ++k)
#pragma unroll
        for (int j = 0; j < 8; ++j) acc[j] += a[k] * e[k + j];
    }
    int base = o * 121 + l0;
#pragma unroll
    for (int j = 0; j < 8; ++j)
      if (l0 + j < 121) out[(size_t)b * 3872 + base + j] = f2b(acc[j]);
  }
}

// ---------------- final row-dot (bf16 input) ----------------
__global__ __launch_bounds__(256) void final_out(const u16* __restrict__ z2,
    const float* __restrict__ W, const float* __restrict__ bias, float* __restrict__ out)
{
  int row = blockIdx.x * 4 + (threadIdx.x >> 6);
  int lane = threadIdx.x & 63;
  const u16* zr = z2 + (size_t)row * 512;
  float s = 0.f;
  for (int i = lane; i < 512; i += 64) s += b2f(zr[i]) * W[i];
#pragma unroll
  for (int off = 32; off > 0; off >>= 1) s += __shfl_down(s, off, 64);
  if (lane == 0) out[row] = s + bias[0];
}

// ---------------- launch ----------------
extern "C" void kernel_launch(void* const* d_in, const int* in_sizes, int n_in,
                              void* d_out, int out_size, void* d_ws, size_t ws_size,
                              hipStream_t stream)
{
  const float* x        = (const float*)d_in[0];
  const int*   ei       = (const int*)d_in[1];
  const int*   batch    = (const int*)d_in[2];
  const int*   tgt      = (const int*)d_in[3];
  const float* gat_W    = (const float*)d_in[4];
  const float* att_src  = (const float*)d_in[5];
  const float* att_dst  = (const float*)d_in[6];
  const float* gat_bias = (const float*)d_in[7];
  const float* gcn_W    = (const float*)d_in[8];
  const float* gcn_bias = (const float*)d_in[9];
  const float* fcg1_W   = (const float*)d_in[10];
  const float* fcg1_b   = (const float*)d_in[11];
  const float* fcg2_W   = (const float*)d_in[12];
  const float* fcg2_b   = (const float*)d_in[13];
  const float* embed    = (const float*)d_in[14];
  const float* convW    = (const float*)d_in[15];
  const float* convb    = (const float*)d_in[16];
  const float* fc1xt_W  = (const float*)d_in[17];
  const float* fc1xt_b  = (const float*)d_in[18];
  const float* fc1_W    = (const float*)d_in[19];
  const float* fc1_b    = (const float*)d_in[20];
  const float* fc2_W    = (const float*)d_in[21];
  const float* fc2_b    = (const float*)d_in[22];
  const float* out_W    = (const float*)d_in[23];
  const float* out_b    = (const float*)d_in[24];

  const int N = in_sizes[0] / FO;      // 40960
  const int E = in_sizes[1] / 2;       // 163840
  const int B = in_sizes[3] / 1000;    // 1024
  const int ET = E + N;

  char* ws = (char*)d_ws;
  size_t off = 0;
  auto alloc = [&](size_t bytes) -> char* {
    char* p = ws + off;
    off = (off + bytes + 255) & ~(size_t)255;
    return p;
  };
  float* buf0  = (float*)alloc((size_t)N * HID * 4);
  float* buf1  = (float*)alloc((size_t)N * 800 * 2);
  u16*   Ab       = (u16*)alloc((size_t)26624 * 256 * 2);
  u16*   convflat = (u16*)alloc((size_t)1024 * 3872 * 2);
  u16*   wt1   = (u16*)alloc((size_t)896 * 96 * 2);
  u16*   wt2   = (u16*)alloc((size_t)896 * 800 * 2);
  u16*   wtg1  = (u16*)alloc((size_t)1536 * 1568 * 2);
  u16*   wtg2  = (u16*)alloc((size_t)128 * 1504 * 2);
  u16*   wtxt  = (u16*)alloc((size_t)128 * 3872 * 2);
  u16*   wtf1  = (u16*)alloc((size_t)1024 * 256 * 2);
  u16*   wtf2  = (u16*)alloc((size_t)512 * 1024 * 2);
  u16*   wtc   = (u16*)alloc((size_t)256 * 1024 * 2);
  float* att   = (float*)alloc((size_t)N * 20 * 4);
  int*   cnt   = (int*)alloc((size_t)N * 4);
  int*   offs  = (int*)alloc((size_t)(N + 1) * 4);
  int*   fillp = (int*)alloc((size_t)N * 4);
  int*   csr   = (int*)alloc((size_t)ET * 4);
  float* dinv  = (float*)alloc((size_t)N * 4);
  u16*   gb    = (u16*)alloc((size_t)B * 1568 * 2);
  int*   bsum  = (int*)alloc((size_t)64 * 4);

  u16*   xb    = (u16*)buf1;
  u16*   Ind   = (u16*)((char*)buf1 + (size_t)N * 96 * 2);
  u16*   x1b   = (u16*)buf1;
  u16*   hb    = (u16*)buf0;
  float* g1f = buf0;
  float* xtf = g1f + (size_t)1024 * 1500;
  float* g2f = xtf + (size_t)1024 * 128;
  float* z1f = g2f + (size_t)1024 * 128;
  float* z2f = z1f + (size_t)1024 * 1024;
  size_t skBytes = ((size_t)1024 * (1500 + 128 + 128 + 1024 + 512)) * 4;
  u16* g1b = (u16*)buf1;
  u16* xcb = g1b + (size_t)1024 * 1504;
  u16* z1b = xcb + (size_t)1024 * 256;
  u16* z2b = z1b + (size_t)1024 * 1024;

  hipMemsetAsync(cnt, 0, (size_t)N * 4, stream);
  hipMemsetAsync(fillp, 0, (size_t)N * 4, stream);

  int nbx = (N * 96 + 255) / 256;
  int nprep = nbx + 84 + 700 + 2352 + 188 + 484 + 256 + 512 + 1024 + 20 + 1024 + (ET + 255) / 256;
  prep_all<<<nprep, 256, 0, stream>>>(
      x, xb, gat_W, wt1, gcn_W, wt2, fcg1_W, wtg1, fcg2_W, wtg2,
      fc1xt_W, wtxt, fc1_W, wtf1, fc2_W, wtf2, convW, wtc,
      att_src, att_dst, tgt, Ind, ei, cnt, N, E);

  int nb1 = 7 * (N / 128);
  int nb2 = 2 * (26624 / 128);
  gemm_dual<<<nb1 + nb2, 256, 0, stream>>>(
      xb, wt1, hb, att, HID, 96, 800, 7, nb1,
      Ind, wtc, Ab, 256, 1024, 256, 2);

  int nblk = (N + 1023) / 1024;
  scan1<<<nblk, 1024, 0, stream>>>(cnt, offs, dinv, bsum, N);
  scan2<<<nblk, 1024, 0, stream>>>(offs, bsum, N, nblk);
  conv_xt<<<B, 256, 0, stream>>>(Ab, embed, convb, convflat);
  fill_csr<<<(ET + 255) / 256, 256, 0, stream>>>(ei, E, N, offs, fillp, csr);

  gat_gather<<<N, 64, 0, stream>>>(hb, att, offs, csr, gat_bias, x1b);

  gemm_mfma<<<dim3(7, N / 128), 256, 0, stream>>>(x1b, wt2, hb, nullptr, HID, 800, 800);

  gcn_pool<<<B, 256, 0, stream>>>(hb, offs, csr, dinv, gcn_bias, batch, N, gb);

  hipMemsetAsync(g1f, 0, skBytes, stream);

  gemm_sk_dual<<<128 + 192, 256, 0, stream>>>(
      convflat, wtxt, xtf, 128, 3872, 256, 1, 8, 128,
      gb, wtg1, g1f, 1500, 1568, 800, 12, 8);
  int nbias = (B * 128 + B * 1504 + 255) / 256;
  bias_dual<<<nbias, 256, 0, stream>>>(
      xtf, fc1xt_b, xcb + 128, B, 128, 128, 256,
      g1f, fcg1_b, g1b, B, 1500, 1504, 1504);

  gemm_sk<<<dim3(1, B / 128, 8), 256, 0, stream>>>(g1b, wtg2, g2f, 128, 1504, 192);
  bias_act_pad<false><<<(B * 128 + 255) / 256, 256, 0, stream>>>(
      g2f, fcg2_b, xcb, B, 128, 128, 256);

  gemm_sk<<<dim3(8, B / 128, 2), 256, 0, stream>>>(xcb, wtf1, z1f, 1024, 256, 128);
  bias_act_pad<true><<<(B * 1024 + 255) / 256, 256, 0, stream>>>(
      z1f, fc1_b, z1b, B, 1024, 1024, 1024);

  gemm_sk<<<dim3(4, B / 128, 4), 256, 0, stream>>>(z1b, wtf2, z2f, 512, 1024, 256);
  bias_act_pad<true><<<(B * 512 + 255) / 256, 256, 0, stream>>>(
      z2f, fc2_b, z2b, B, 512, 512, 512);

  final_out<<<B / 4, 256, 0, stream>>>(z2b, out_W, out_b, (float*)d_out);
}

// Round 22
// 440.145 us; speedup vs baseline: 1.0173x; 1.0173x over previous
//
#include <hip/hip_runtime.h>

typedef __attribute__((ext_vector_type(4))) float f32x4;
typedef __attribute__((ext_vector_type(8))) short bf16x8;
typedef __attribute__((ext_vector_type(8))) unsigned short u16x8;
typedef unsigned short u16;

#define HID 780
#define NH 10
#define FO 78

__device__ inline u16 f2b(float f) {  // fp32 -> bf16 RNE
  unsigned u = __float_as_uint(f);
  unsigned r = (u + 0x7fff + ((u >> 16) & 1)) >> 16;
  return (u16)r;
}
__device__ inline float b2f(u16 b) { return __uint_as_float(((unsigned)b) << 16); }

__device__ inline void gld16(const u16* g, u16* l) {
  __builtin_amdgcn_global_load_lds(
      (const __attribute__((address_space(1))) unsigned int*)g,
      (__attribute__((address_space(3))) unsigned int*)l, 16, 0, 0);
}

__device__ inline int swz_bid() {
  int gx = gridDim.x, gy = gridDim.y, gz = gridDim.z;
  int nwg = gx * gy * gz;
  int bid = (blockIdx.z * gy + blockIdx.y) * gx + blockIdx.x;
  if ((nwg & 7) == 0) bid = (bid & 7) * (nwg >> 3) + (bid >> 3);
  return bid;
}

// ---------------- shared GEMM core: 3-deep pipeline, counted vmcnt ----------------
// LDS: 3 buffers x (128x32 u16) per operand = 48KB. Loads for tiles k..k+2 stay
// in flight across raw s_barriers; per-tile wait is vmcnt(8)/(4)/(0) (in-order
// retirement, m135). Stage for tile k+3 is issued between the read-drain
// barrier and the MFMAs, so each DMA has ~3 iterations to land.
__device__ __forceinline__ void gemm_core(const u16* __restrict__ A,
    const u16* __restrict__ BT, u16* __restrict__ C, float* __restrict__ att_out,
    int Ncols, int KP, int ldc, int bx, int by,
    u16 (*As)[4096], u16 (*Bs)[4096])
{
  const int tid = threadIdx.x;
  const int row0 = by << 7, col0 = bx << 7;
  const int l = tid & 63, wid = tid >> 6;
  const int wr = wid >> 1, wc = wid & 1;
  const int lr = l & 15, lk = l >> 4;
  const int c0 = (wid << 6) + l, c1 = 256 + c0;
  const u16* gA0 = A + (size_t)(row0 + (c0 >> 2)) * KP + ((c0 & 3) << 3);
  const u16* gA1 = A + (size_t)(row0 + (c1 >> 2)) * KP + ((c1 & 3) << 3);
  const u16* gB0 = BT + (size_t)(col0 + (c0 >> 2)) * KP + ((c0 & 3) << 3);
  const u16* gB1 = BT + (size_t)(col0 + (c1 >> 2)) * KP + ((c1 & 3) << 3);
  const int d0 = (wid << 6) << 3, d1 = (256 + (wid << 6)) << 3;

  f32x4 acc[4][4];
#pragma unroll
  for (int i = 0; i < 4; ++i)
#pragma unroll
    for (int j = 0; j < 4; ++j) acc[i][j] = (f32x4){0.f, 0.f, 0.f, 0.f};

  const int niter = KP >> 5;
  const int npre = niter < 3 ? niter : 3;
  for (int t = 0; t < npre; ++t) {
    int kk = t << 5;
    gld16(gA0 + kk, &As[t][d0]); gld16(gA1 + kk, &As[t][d1]);
    gld16(gB0 + kk, &Bs[t][d0]); gld16(gB1 + kk, &Bs[t][d1]);
  }

  int cb = 0;
  for (int k = 0; k < niter; ++k) {
    // wait until tile k's 4 loads (oldest outstanding) have retired
    if (k + 2 < niter)      asm volatile("s_waitcnt vmcnt(8)" ::: "memory");
    else if (k + 1 < niter) asm volatile("s_waitcnt vmcnt(4)" ::: "memory");
    else                    asm volatile("s_waitcnt vmcnt(0)" ::: "memory");
    __builtin_amdgcn_sched_barrier(0);
    __builtin_amdgcn_s_barrier();          // all waves' tile-k loads landed
    asm volatile("" ::: "memory");

    const u16* Ac = As[cb];
    const u16* Bc = Bs[cb];
    bf16x8 af[4], bfr[4];
#pragma unroll
    for (int fm = 0; fm < 4; ++fm)
      af[fm] = *(const bf16x8*)&Ac[((wr * 64 + fm * 16 + lr) << 5) + (lk << 3)];
#pragma unroll
    for (int fn = 0; fn < 4; ++fn)
      bfr[fn] = *(const bf16x8*)&Bc[((wc * 64 + fn * 16 + lr) << 5) + (lk << 3)];

    if (k + 3 < niter) {
      // drain own ds_reads, barrier (all waves done reading buf cb), then
      // overwrite buf cb with tile k+3 while MFMAs run
      asm volatile("s_waitcnt lgkmcnt(0)" ::: "memory");
      __builtin_amdgcn_sched_barrier(0);
      __builtin_amdgcn_s_barrier();
      asm volatile("" ::: "memory");
      int kn = (k + 3) << 5;
      gld16(gA0 + kn, &As[cb][d0]); gld16(gA1 + kn, &As[cb][d1]);
      gld16(gB0 + kn, &Bs[cb][d0]); gld16(gB1 + kn, &Bs[cb][d1]);
      __builtin_amdgcn_sched_barrier(0);
    }

#pragma unroll
    for (int fm = 0; fm < 4; ++fm)
#pragma unroll
      for (int fn = 0; fn < 4; ++fn)
        acc[fm][fn] = __builtin_amdgcn_mfma_f32_16x16x32_bf16(af[fm], bfr[fn], acc[fm][fn], 0, 0, 0);

    cb = (cb == 2) ? 0 : cb + 1;
  }
#pragma unroll
  for (int fm = 0; fm < 4; ++fm)
#pragma unroll
    for (int fn = 0; fn < 4; ++fn) {
      int col = col0 + wc * 64 + fn * 16 + lr;
      f32x4 v = acc[fm][fn];
      int rbase = row0 + wr * 64 + fm * 16 + lk * 4;
      if (col < Ncols) {
#pragma unroll
        for (int j = 0; j < 4; ++j)
          C[(size_t)(rbase + j) * ldc + col] = f2b(v[j]);
      } else {
        if (att_out != nullptr && col < Ncols + 20) {
          int c = col - Ncols;
#pragma unroll
          for (int j = 0; j < 4; ++j)
            att_out[(size_t)(rbase + j) * 20 + c] = v[j];
        }
        if (col < ldc) {
#pragma unroll
          for (int j = 0; j < 4; ++j) C[(size_t)(rbase + j) * ldc + col] = 0;
        }
      }
    }
}

__global__ __launch_bounds__(256) void gemm_mfma(const u16* __restrict__ A,
    const u16* __restrict__ BT, u16* __restrict__ C, float* __restrict__ att_out,
    int Ncols, int KP, int ldc)
{
  __shared__ u16 As[3][4096];
  __shared__ u16 Bs[3][4096];
  int t = swz_bid();
  gemm_core(A, BT, C, att_out, Ncols, KP, ldc, t % gridDim.x, t / gridDim.x, As, Bs);
}

__global__ __launch_bounds__(256) void gemm_dual(
    const u16* __restrict__ A1, const u16* __restrict__ B1, u16* __restrict__ C1,
    float* __restrict__ att1, int N1, int K1, int l1, int gx1, int nb1,
    const u16* __restrict__ A2, const u16* __restrict__ B2, u16* __restrict__ C2,
    int N2, int K2, int l2, int gx2)
{
  __shared__ u16 As[3][4096];
  __shared__ u16 Bs[3][4096];
  int bi = blockIdx.x;
  if (bi < nb1) {
    int t = bi;
    if ((nb1 & 7) == 0) t = (bi & 7) * (nb1 >> 3) + (bi >> 3);
    gemm_core(A1, B1, C1, att1, N1, K1, l1, t % gx1, t / gx1, As, Bs);
  } else {
    int nb2 = gridDim.x - nb1, b2 = bi - nb1;
    int t = b2;
    if ((nb2 & 7) == 0) t = (b2 & 7) * (nb2 >> 3) + (b2 >> 3);
    gemm_core(A2, B2, C2, nullptr, N2, K2, l2, t % gx2, t / gx2, As, Bs);
  }
}

// ---------------- split-K core: fp32 atomic partials, 2-phase (unchanged) ----------------
__device__ __forceinline__ void sk_core(const u16* __restrict__ A,
    const u16* __restrict__ BT, float* __restrict__ C,
    int Ncols, int KP, int kchunk, int bx, int by, int bz,
    u16 (*As)[4096], u16 (*Bs)[4096])
{
  const int tid = threadIdx.x;
  const int row0 = by << 7, col0 = bx << 7;
  const int kbeg = bz * kchunk;
  const int kend = min(KP, kbeg + kchunk);
  const int l = tid & 63, wid = tid >> 6;
  const int wr = wid >> 1, wc = wid & 1;
  const int lr = l & 15, lk = l >> 4;
  const int c0 = (wid << 6) + l, c1 = 256 + c0;
  const u16* gA0 = A + (size_t)(row0 + (c0 >> 2)) * KP + ((c0 & 3) << 3) + kbeg;
  const u16* gA1 = A + (size_t)(row0 + (c1 >> 2)) * KP + ((c1 & 3) << 3) + kbeg;
  const u16* gB0 = BT + (size_t)(col0 + (c0 >> 2)) * KP + ((c0 & 3) << 3) + kbeg;
  const u16* gB1 = BT + (size_t)(col0 + (c1 >> 2)) * KP + ((c1 & 3) << 3) + kbeg;
  const int d0 = (wid << 6) << 3, d1 = (256 + (wid << 6)) << 3;

  f32x4 acc[4][4];
#pragma unroll
  for (int i = 0; i < 4; ++i)
#pragma unroll
    for (int j = 0; j < 4; ++j) acc[i][j] = (f32x4){0.f, 0.f, 0.f, 0.f};

  gld16(gA0, &As[0][d0]); gld16(gA1, &As[0][d1]);
  gld16(gB0, &Bs[0][d0]); gld16(gB1, &Bs[0][d1]);
  __syncthreads();

  int cur = 0;
  for (int k0 = kbeg; k0 < kend; k0 += 32) {
    if (k0 + 32 < kend) {
      int nx = cur ^ 1, kn = k0 + 32 - kbeg;
      gld16(gA0 + kn, &As[nx][d0]); gld16(gA1 + kn, &As[nx][d1]);
      gld16(gB0 + kn, &Bs[nx][d0]); gld16(gB1 + kn, &Bs[nx][d1]);
    }
    const u16* Ac = As[cur];
    const u16* Bc = Bs[cur];
    bf16x8 af[4], bfr[4];
#pragma unroll
    for (int fm = 0; fm < 4; ++fm)
      af[fm] = *(const bf16x8*)&Ac[((wr * 64 + fm * 16 + lr) << 5) + (lk << 3)];
#pragma unroll
    for (int fn = 0; fn < 4; ++fn)
      bfr[fn] = *(const bf16x8*)&Bc[((wc * 64 + fn * 16 + lr) << 5) + (lk << 3)];
#pragma unroll
    for (int fm = 0; fm < 4; ++fm)
#pragma unroll
      for (int fn = 0; fn < 4; ++fn)
        acc[fm][fn] = __builtin_amdgcn_mfma_f32_16x16x32_bf16(af[fm], bfr[fn], acc[fm][fn], 0, 0, 0);
    __syncthreads();
    cur ^= 1;
  }
#pragma unroll
  for (int fm = 0; fm < 4; ++fm)
#pragma unroll
    for (int fn = 0; fn < 4; ++fn) {
      int col = col0 + wc * 64 + fn * 16 + lr;
      if (col < Ncols) {
        f32x4 v = acc[fm][fn];
        int rbase = row0 + wr * 64 + fm * 16 + lk * 4;
#pragma unroll
        for (int j = 0; j < 4; ++j)
          atomicAdd(&C[(size_t)(rbase + j) * Ncols + col], v[j]);
      }
    }
}

__global__ __launch_bounds__(256) void gemm_sk(const u16* __restrict__ A,
    const u16* __restrict__ BT, float* __restrict__ C,
    int Ncols, int KP, int kchunk)
{
  __shared__ u16 As[2][4096];
  __shared__ u16 Bs[2][4096];
  int t = swz_bid();
  int bx = t % gridDim.x;
  int by = (t / gridDim.x) % gridDim.y;
  int bz = t / (gridDim.x * gridDim.y);
  sk_core(A, BT, C, Ncols, KP, kchunk, bx, by, bz, As, Bs);
}

__global__ __launch_bounds__(256) void gemm_sk_dual(
    const u16* __restrict__ A1, const u16* __restrict__ B1, float* __restrict__ C1,
    int N1, int K1, int kc1, int gx1, int gy1, int nb1,
    const u16* __restrict__ A2, const u16* __restrict__ B2, float* __restrict__ C2,
    int N2, int K2, int kc2, int gx2, int gy2)
{
  __shared__ u16 As[2][4096];
  __shared__ u16 Bs[2][4096];
  int bi = blockIdx.x;
  if (bi < nb1) {
    int t = bi;
    if ((nb1 & 7) == 0) t = (bi & 7) * (nb1 >> 3) + (bi >> 3);
    sk_core(A1, B1, C1, N1, K1, kc1, t % gx1, (t / gx1) % gy1, t / (gx1 * gy1), As, Bs);
  } else {
    int nb2 = gridDim.x - nb1, b2 = bi - nb1;
    int t = b2;
    if ((nb2 & 7) == 0) t = (b2 & 7) * (nb2 >> 3) + (b2 >> 3);
    sk_core(A2, B2, C2, N2, K2, kc2, t % gx2, (t / gx2) % gy2, t / (gx2 * gy2), As, Bs);
  }
}

// fp32 compact [M][N] -> bf16 [M][ldco] with bias/relu, zero-pad cols [N,padTo)
template<bool RELU>
__global__ void bias_act_pad(const float* __restrict__ Cf,
    const float* __restrict__ bias, u16* __restrict__ out,
    int M, int N, int padTo, int ldco)
{
  int idx = blockIdx.x * 256 + threadIdx.x;
  if (idx >= M * padTo) return;
  int r = idx / padTo, c = idx - r * padTo;
  if (c < N) {
    float v = Cf[(size_t)r * N + c] + bias[c];
    if (RELU) v = v > 0.f ? v : 0.f;
    out[(size_t)r * ldco + c] = f2b(v);
  } else {
    out[(size_t)r * ldco + c] = 0;
  }
}

__global__ void bias_dual(const float* __restrict__ C1, const float* __restrict__ b1,
    u16* __restrict__ o1, int M1, int N1, int p1, int l1,
    const float* __restrict__ C2, const float* __restrict__ b2,
    u16* __restrict__ o2, int M2, int N2, int p2, int l2)
{
  int idx = blockIdx.x * 256 + threadIdx.x;
  int t1 = M1 * p1;
  if (idx < t1) {
    int r = idx / p1, c = idx - r * p1;
    if (c < N1) o1[(size_t)r * l1 + c] = f2b(C1[(size_t)r * N1 + c] + b1[c]);
    else o1[(size_t)r * l1 + c] = 0;
    return;
  }
  idx -= t1;
  if (idx >= M2 * p2) return;
  int r = idx / p2, c = idx - r * p2;
  if (c < N2) {
    float v = C2[(size_t)r * N2 + c] + b2[c];
    v = v > 0.f ? v : 0.f;
    o2[(size_t)r * l2 + c] = f2b(v);
  } else {
    o2[(size_t)r * l2 + c] = 0;
  }
}

// ---------------- fused prep ----------------
__device__ inline void wtile(const float* __restrict__ W, u16* __restrict__ WT,
    int K, int Ncol, int KP, int NP, int bx, int by, int skip_lo, int skip_hi,
    u16 (*tbuf)[33])
{
  int tn0 = bx << 5, tk0 = by << 5;
  int lx = threadIdx.x & 31, ly = threadIdx.x >> 5;
#pragma unroll
  for (int r = 0; r < 32; r += 8) {
    int k = tk0 + ly + r, n = tn0 + lx;
    tbuf[ly + r][lx] = (k < K && n < Ncol) ? f2b(W[(size_t)k * Ncol + n]) : (u16)0;
  }
  __syncthreads();
#pragma unroll
  for (int r = 0; r < 32; r += 8) {
    int n = tn0 + ly + r, k = tk0 + lx;
    if (n < NP && k < KP && !(n >= skip_lo && n < skip_hi))
      WT[(size_t)n * KP + k] = tbuf[lx][ly + r];
  }
}

__global__ __launch_bounds__(256) void prep_all(
    const float* __restrict__ x, u16* __restrict__ xb,
    const float* __restrict__ gat_W, u16* __restrict__ wt1,
    const float* __restrict__ gcn_W, u16* __restrict__ wt2,
    const float* __restrict__ fcg1_W, u16* __restrict__ wtg1,
    const float* __restrict__ fcg2_W, u16* __restrict__ wtg2,
    const float* __restrict__ fc1xt_W, u16* __restrict__ wtxt,
    const float* __restrict__ fc1_W, u16* __restrict__ wtf1,
    const float* __restrict__ fc2_W, u16* __restrict__ wtf2,
    const float* __restrict__ convW, u16* __restrict__ wtc,
    const float* __restrict__ asv, const float* __restrict__ adv,
    const int* __restrict__ tgt, u16* __restrict__ Ind,
    const int* __restrict__ ei, int* __restrict__ cnt, int N, int E)
{
  __shared__ u16 tbuf[32][33];
  __shared__ unsigned char tl[1000];
  int bi = blockIdx.x, tid = threadIdx.x;
  const int s0 = (N * 96 + 255) / 256;
  if (bi < s0) {
    int idx = bi * 256 + tid;
    if (idx < N * 96) {
      int r = idx / 96, c = idx - r * 96;
      xb[idx] = (c < FO) ? f2b(x[(size_t)r * FO + c]) : (u16)0;
    }
    return;
  }
  bi -= s0;
  if (bi < 84)   { wtile(gat_W,  wt1,  FO,   HID,  96,   896,  bi % 28, bi / 28, 780, 800, tbuf); return; }
  bi -= 84;
  if (bi < 700)  { wtile(gcn_W,  wt2,  HID,  HID,  800,  896,  bi % 28, bi / 28, 1 << 30, 0, tbuf); return; }
  bi -= 700;
  if (bi < 2352) { wtile(fcg1_W, wtg1, 1560, 1500, 1568, 1536, bi % 48, bi / 48, 1 << 30, 0, tbuf); return; }
  bi -= 2352;
  if (bi < 188)  { wtile(fcg2_W, wtg2, 1500, 128,  1504, 128,  bi % 4,  bi / 4,  1 << 30, 0, tbuf); return; }
  bi -= 188;
  if (bi < 484)  { wtile(fc1xt_W, wtxt, 3872, 128, 3872, 128,  bi % 4,  bi / 4,  1 << 30, 0, tbuf); return; }
  bi -= 484;
  if (bi < 256)  { wtile(fc1_W,  wtf1, 256,  1024, 256,  1024, bi % 32, bi / 32, 1 << 30, 0, tbuf); return; }
  bi -= 256;
  if (bi < 512)  { wtile(fc2_W,  wtf2, 1024, 512,  1024, 512,  bi % 16, bi / 16, 1 << 30, 0, tbuf); return; }
  bi -= 512;
  if (bi < 1024) {
    int idx = bi * 256 + tid;
    int ok = idx >> 10, c = idx & 1023;
    int o = ok >> 3, k = ok & 7;
    wtc[idx] = (c < 1000) ? f2b(convW[(size_t)o * 8000 + c * 8 + k]) : (u16)0;
    return;
  }
  bi -= 1024;
  if (bi < 20) {
    int j = bi, k = tid;
    if (k >= 96) return;
    float s = 0.f;
    if (k < FO) {
      int h = (j < 10) ? j : j - 10;
      const float* av = ((j < 10) ? asv : adv) + h * FO;
      const float* wr = gat_W + (size_t)k * HID + h * FO;
      for (int f = 0; f < FO; ++f) s += wr[f] * av[f];
    }
    wt1[(size_t)(HID + j) * 96 + k] = f2b(s);
    return;
  }
  bi -= 20;
  if (bi < 1024) {
    int b = bi;
    for (int i = tid; i < 1000; i += 256) tl[i] = (unsigned char)tgt[b * 1000 + i];
    __syncthreads();
    u16* out = Ind + (size_t)b * 26 * 1024;
    for (int ci = tid; ci < 26 * 128; ci += 256) {
      int v = ci >> 7, c0 = (ci & 127) << 3;
      u16x8 w;
#pragma unroll
      for (int j = 0; j < 8; ++j) {
        int c = c0 + j;
        w[j] = (c < 1000 && tl[c] == v) ? (u16)0x3F80 : (u16)0;
      }
      *(u16x8*)(out + v * 1024 + c0) = w;
    }
    return;
  }
  bi -= 1024;
  {
    int e = bi * 256 + tid;
    if (e >= E + N) return;
    int dst = (e < E) ? ei[E + e] : (e - E);
    atomicAdd(&cnt[dst], 1);
  }
}

// ---------------- multi-block scan ----------------
__global__ __launch_bounds__(1024) void scan1(const int* __restrict__ cnt,
    int* __restrict__ offs, float* __restrict__ dinv, int* __restrict__ bsum, int N)
{
  __shared__ int sc[1024];
  int b = blockIdx.x, tid = threadIdx.x;
  int g = b * 1024 + tid;
  int c = (g < N) ? cnt[g] : 0;
  sc[tid] = c;
  __syncthreads();
  for (int off = 1; off < 1024; off <<= 1) {
    int v = sc[tid];
    int add = (tid >= off) ? sc[tid - off] : 0;
    __syncthreads();
    sc[tid] = v + add;
    __syncthreads();
  }
  if (g < N) {
    offs[g] = sc[tid] - c;
    dinv[g] = c > 0 ? rsqrtf((float)c) : 0.f;
  }
  if (tid == 1023) bsum[b] = sc[1023];
}

__global__ __launch_bounds__(1024) void scan2(int* __restrict__ offs,
    const int* __restrict__ bsum, int N, int nblk)
{
  int b = blockIdx.x, tid = threadIdx.x;
  int base = 0;
  for (int j = 0; j < b; ++j) base += bsum[j];
  int g = b * 1024 + tid;
  if (g < N && b > 0) offs[g] += base;
  if (b == nblk - 1 && tid == 1023) offs[N] = base + bsum[b];
}

__global__ void fill_csr(const int* __restrict__ ei, int E, int N,
    const int* __restrict__ offs, int* __restrict__ fillpos, int* __restrict__ csr_src)
{
  int e = blockIdx.x * 256 + threadIdx.x;
  if (e >= E + N) return;
  int src, dst;
  if (e < E) { src = ei[e]; dst = ei[E + e]; }
  else { src = e - E; dst = e - E; }
  int p = offs[dst] + atomicAdd(&fillpos[dst], 1);
  csr_src[p] = src;
}

// ---------------- GAT gather ----------------
#define CH 48
__global__ __launch_bounds__(64) void gat_gather(const u16* __restrict__ h,
    const float* __restrict__ att,
    const int* __restrict__ offs, const int* __restrict__ csr_src,
    const float* __restrict__ gat_bias, u16* __restrict__ x1b)
{
  int n = blockIdx.x, lane = threadIdx.x;
  int o0 = offs[n], deg = offs[n + 1] - o0;
  __shared__ float ad[NH], ssum[NH];
  __shared__ float wbuf[CH][NH];
  __shared__ int slist[CH];
  if (lane < NH) { ad[lane] = att[n * 20 + 10 + lane]; ssum[lane] = 0.f; }
  const int s0 = lane, s1 = 64 + lane;
  const bool a1 = s1 < 100;
  int hA0 = min((s0 * 8) / FO, NH - 1), bb0 = FO * ((s0 * 8) / FO + 1) - s0 * 8;
  int hB0 = min((s0 * 8) / FO + 1, NH - 1);
  int hA1 = min((s1 * 8) / FO, NH - 1), bb1 = FO * ((s1 * 8) / FO + 1) - s1 * 8;
  int hB1 = min((s1 * 8) / FO + 1, NH - 1);
  float acc0[8], acc1[8];
#pragma unroll
  for (int j = 0; j < 8; ++j) { acc0[j] = 0.f; acc1[j] = 0.f; }
  __syncthreads();

  for (int e0 = 0; e0 < deg; e0 += CH) {
    int ce = min(CH, deg - e0);
    for (int idx = lane; idx < ce * NH; idx += 64) {
      int e = idx / NH, hd = idx - e * NH;
      int s = csr_src[o0 + e0 + e];
      float l = att[s * 20 + hd] + ad[hd];
      l = l > 0.f ? l : 0.2f * l;
      float w = __expf(l);
      wbuf[e][hd] = w;
      atomicAdd(&ssum[hd], w);
    }
    for (int idx = lane; idx < ce; idx += 64) slist[idx] = csr_src[o0 + e0 + idx];
    __syncthreads();
    for (int e = 0; e < ce; ++e) {
      const u16* hs = h + (size_t)slist[e] * 800;
      u16x8 v0 = *(const u16x8*)(hs + s0 * 8);
      float wA0 = wbuf[e][hA0], wB0 = wbuf[e][hB0];
#pragma unroll
      for (int j = 0; j < 8; ++j)
        acc0[j] += (j < bb0 ? wA0 : wB0) * b2f(v0[j]);
      if (a1) {
        u16x8 v1 = *(const u16x8*)(hs + s1 * 8);
        float wA1 = wbuf[e][hA1], wB1 = wbuf[e][hB1];
#pragma unroll
        for (int j = 0; j < 8; ++j)
          acc1[j] += (j < bb1 ? wA1 : wB1) * b2f(v1[j]);
      }
    }
    __syncthreads();
  }
  float iA0 = 1.f / (ssum[hA0] + 1e-16f), iB0 = 1.f / (ssum[hB0] + 1e-16f);
  u16x8 o0v;
#pragma unroll
  for (int j = 0; j < 8; ++j) {
    int f = s0 * 8 + j;
    float v = acc0[j] * (j < bb0 ? iA0 : iB0) + gat_bias[f];
    o0v[j] = f2b(v > 0.f ? v : 0.f);
  }
  *(u16x8*)(x1b + (size_t)n * 800 + s0 * 8) = o0v;
  if (a1) {
    float iA1 = 1.f / (ssum[hA1] + 1e-16f), iB1 = 1.f / (ssum[hB1] + 1e-16f);
    u16x8 o1v;
#pragma unroll
    for (int j = 0; j < 8; ++j) {
      int f = s1 * 8 + j;
      if (f < HID) {
        float v = acc1[j] * (j < bb1 ? iA1 : iB1) + gat_bias[f];
        o1v[j] = f2b(v > 0.f ? v : 0.f);
      } else o1v[j] = 0;
    }
    *(u16x8*)(x1b + (size_t)n * 800 + s1 * 8) = o1v;
  }
}

// ---------------- GCN gather + per-graph pooling: shfl-staged edges ----------------
__global__ __launch_bounds__(256) void gcn_pool(const u16* __restrict__ h2,
    const int* __restrict__ offs, const int* __restrict__ csr_src,
    const float* __restrict__ dinv, const float* __restrict__ gcn_bias,
    const int* __restrict__ batch, int N, u16* __restrict__ gb)
{
  int gi = blockIdx.x, tid = threadIdx.x;
  int grp = tid >> 6, lane = tid & 63;
  __shared__ int se[2];
  __shared__ float smx[HID];
  __shared__ float ssm[HID];
  for (int f = tid; f < HID; f += 256) { smx[f] = 0.f; ssm[f] = 0.f; }
  if (tid < 2) {
    int target = gi + tid;
    int lo = 0, hi = N;
    while (lo < hi) { int mid = (lo + hi) >> 1; if (batch[mid] < target) lo = mid + 1; else hi = mid; }
    se[tid] = lo;
  }
  __syncthreads();
  int s = se[0], e = se[1];
  const int s0 = lane, s1 = 64 + lane;
  const bool a1 = s1 < 100;
  float bv0[8], bv1[8];
#pragma unroll
  for (int j = 0; j < 8; ++j) {
    int f0 = s0 * 8 + j, f1 = s1 * 8 + j;
    bv0[j] = gcn_bias[f0];
    bv1[j] = (a1 && f1 < HID) ? gcn_bias[f1] : 0.f;
  }
  float mx0[8], sm0[8], mx1[8], sm1[8];
#pragma unroll
  for (int j = 0; j < 8; ++j) { mx0[j] = 0.f; sm0[j] = 0.f; mx1[j] = 0.f; sm1[j] = 0.f; }

  for (int n = s + grp; n < e; n += 4) {
    int o0 = offs[n], deg = offs[n + 1] - o0;
    float dn = dinv[n];
    float acc0[8], acc1[8];
#pragma unroll
    for (int j = 0; j < 8; ++j) { acc0[j] = 0.f; acc1[j] = 0.f; }
    for (int eb = 0; eb < deg; eb += 64) {
      int ce = min(64, deg - eb);
      int   src_l = (lane < ce) ? csr_src[o0 + eb + lane] : 0;
      float c_l   = (lane < ce) ? dn * dinv[src_l] : 0.f;
      int   sc = __shfl(src_l, 0, 64);
      float cc = __shfl(c_l, 0, 64);
      const u16* hr = h2 + (size_t)sc * 800;
      u16x8 v0 = *(const u16x8*)(hr + s0 * 8);
      u16x8 v1 = a1 ? *(const u16x8*)(hr + s1 * 8) : v0;
      for (int ed = 0; ed < ce; ++ed) {
        u16x8 n0 = v0, n1 = v1;
        float nc = 0.f;
        if (ed + 1 < ce) {
          int ns = __shfl(src_l, ed + 1, 64);
          nc = __shfl(c_l, ed + 1, 64);
          const u16* nh = h2 + (size_t)ns * 800;
          n0 = *(const u16x8*)(nh + s0 * 8);
          if (a1) n1 = *(const u16x8*)(nh + s1 * 8);
        }
#pragma unroll
        for (int j = 0; j < 8; ++j) acc0[j] += cc * b2f(v0[j]);
        if (a1) {
#pragma unroll
          for (int j = 0; j < 8; ++j) acc1[j] += cc * b2f(v1[j]);
        }
        v0 = n0; v1 = n1; cc = nc;
      }
    }
#pragma unroll
    for (int j = 0; j < 8; ++j) {
      float v = acc0[j] + bv0[j];
      v = v > 0.f ? v : 0.f;
      mx0[j] = fmaxf(mx0[j], v); sm0[j] += v;
      float w = acc1[j] + bv1[j];
      w = w > 0.f ? w : 0.f;
      mx1[j] = fmaxf(mx1[j], w); sm1[j] += w;
    }
  }
#pragma unroll
  for (int j = 0; j < 8; ++j) {
    int f0 = s0 * 8 + j;
    atomicMax((unsigned*)&smx[f0], __float_as_uint(mx0[j]));
    atomicAdd(&ssm[f0], sm0[j]);
    int f1 = s1 * 8 + j;
    if (a1 && f1 < HID) {
      atomicMax((unsigned*)&smx[f1], __float_as_uint(mx1[j]));
      atomicAdd(&ssm[f1], sm1[j]);
    }
  }
  __syncthreads();
  float inv = 1.f / fmaxf((float)(e - s), 1.f);
  for (int f = tid; f < HID; f += 256) {
    gb[(size_t)gi * 1568 + f] = f2b(smx[f]);
    gb[(size_t)gi * 1568 + HID + f] = f2b(ssm[f] * inv);
  }
  if (tid < 8) gb[(size_t)gi * 1568 + 1560 + tid] = 0;
}

// ---------------- conv from bf16 A ----------------
__global__ __launch_bounds__(256) void conv_xt(const u16* __restrict__ Aall,
    const float* __restrict__ embed, const float* __restrict__ cbias,
    u16* __restrict__ out)
{
  int b = blockIdx.x, tid = threadIdx.x;
  __shared__ __align__(16) float Al[6656];
  __shared__ __align__(16) float el[3360];
  const u16* Ab = Aall + (size_t)b * 6656;
  for (int i = tid; i < 6656; i += 256) Al[i] = b2f(Ab[i]);
  for (int i = tid; i < 3328; i += 256) el[i] = embed[i];
  if (tid < 32) el[3328 + tid] = 0.f;
  __syncthreads();
  for (int grp = tid; grp < 512; grp += 256) {
    int o = grp >> 4;
    int l0 = (grp & 15) << 3;
    float cb = cbias[o];
    float acc[8];
#pragma unroll
    for (int j = 0; j < 8; ++j) acc[j] = cb;
    for (int v = 0; v < 26; ++v) {
      const float* ap = &Al[v * 256 + (o << 3)];
      f32x4 a0 = *(const f32x4*)ap;
      f32x4 a1 = *(const f32x4*)(ap + 4);
      const float* ep = &el[v * 128 + l0];
      f32x4 e0 = *(const f32x4*)ep;
      f32x4 e1 = *(const f32x4*)(ep + 4);
      f32x4 e2 = *(const f32x4*)(ep + 8);
      f32x4 e3 = *(const f32x4*)(ep + 12);
      float a[8] = { a0[0], a0[1], a0[2], a0[3], a1[0], a1[1], a1[2], a1[3] };
      float e[16] = { e0[0], e0[1], e0[2], e0[3], e1[0], e1[1], e1[2], e1[3],
                      e2[0], e2[1], e2[2], e2[3], e3[0], e3[1], e3[2], e3[3] };
#pragma unroll
      for (int k = 0; k < 8; ++k)
#pragma unroll
        for (int j = 0; j < 8; ++j) acc[j] += a[k] * e[k + j];
    }
    int base = o * 121 + l0;
#pragma unroll
    for (int j = 0; j < 8; ++j)
      if (l0 + j < 121) out[(size_t)b * 3872 + base + j] = f2b(acc[j]);
  }
}

// ---------------- final row-dot (bf16 input) ----------------
__global__ __launch_bounds__(256) void final_out(const u16* __restrict__ z2,
    const float* __restrict__ W, const float* __restrict__ bias, float* __restrict__ out)
{
  int row = blockIdx.x * 4 + (threadIdx.x >> 6);
  int lane = threadIdx.x & 63;
  const u16* zr = z2 + (size_t)row * 512;
  float s = 0.f;
  for (int i = lane; i < 512; i += 64) s += b2f(zr[i]) * W[i];
#pragma unroll
  for (int off = 32; off > 0; off >>= 1) s += __shfl_down(s, off, 64);
  if (lane == 0) out[row] = s + bias[0];
}

// ---------------- launch ----------------
extern "C" void kernel_launch(void* const* d_in, const int* in_sizes, int n_in,
                              void* d_out, int out_size, void* d_ws, size_t ws_size,
                              hipStream_t stream)
{
  const float* x        = (const float*)d_in[0];
  const int*   ei       = (const int*)d_in[1];
  const int*   batch    = (const int*)d_in[2];
  const int*   tgt      = (const int*)d_in[3];
  const float* gat_W    = (const float*)d_in[4];
  const float* att_src  = (const float*)d_in[5];
  const float* att_dst  = (const float*)d_in[6];
  const float* gat_bias = (const float*)d_in[7];
  const float* gcn_W    = (const float*)d_in[8];
  const float* gcn_bias = (const float*)d_in[9];
  const float* fcg1_W   = (const float*)d_in[10];
  const float* fcg1_b   = (const float*)d_in[11];
  const float* fcg2_W   = (const float*)d_in[12];
  const float* fcg2_b   = (const float*)d_in[13];
  const float* embed    = (const float*)d_in[14];
  const float* convW    = (const float*)d_in[15];
  const float* convb    = (const float*)d_in[16];
  const float* fc1xt_W  = (const float*)d_in[17];
  const float* fc1xt_b  = (const float*)d_in[18];
  const float* fc1_W    = (const float*)d_in[19];
  const float* fc1_b    = (const float*)d_in[20];
  const float* fc2_W    = (const float*)d_in[21];
  const float* fc2_b    = (const float*)d_in[22];
  const float* out_W    = (const float*)d_in[23];
  const float* out_b    = (const float*)d_in[24];

  const int N = in_sizes[0] / FO;      // 40960
  const int E = in_sizes[1] / 2;       // 163840
  const int B = in_sizes[3] / 1000;    // 1024
  const int ET = E + N;

  char* ws = (char*)d_ws;
  size_t off = 0;
  auto alloc = [&](size_t bytes) -> char* {
    char* p = ws + off;
    off = (off + bytes + 255) & ~(size_t)255;
    return p;
  };
  float* buf0  = (float*)alloc((size_t)N * HID * 4);
  float* buf1  = (float*)alloc((size_t)N * 800 * 2);
  u16*   Ab       = (u16*)alloc((size_t)26624 * 256 * 2);
  u16*   convflat = (u16*)alloc((size_t)1024 * 3872 * 2);
  u16*   wt1   = (u16*)alloc((size_t)896 * 96 * 2);
  u16*   wt2   = (u16*)alloc((size_t)896 * 800 * 2);
  u16*   wtg1  = (u16*)alloc((size_t)1536 * 1568 * 2);
  u16*   wtg2  = (u16*)alloc((size_t)128 * 1504 * 2);
  u16*   wtxt  = (u16*)alloc((size_t)128 * 3872 * 2);
  u16*   wtf1  = (u16*)alloc((size_t)1024 * 256 * 2);
  u16*   wtf2  = (u16*)alloc((size_t)512 * 1024 * 2);
  u16*   wtc   = (u16*)alloc((size_t)256 * 1024 * 2);
  float* att   = (float*)alloc((size_t)N * 20 * 4);
  int*   cnt   = (int*)alloc((size_t)N * 4);
  int*   offs  = (int*)alloc((size_t)(N + 1) * 4);
  int*   fillp = (int*)alloc((size_t)N * 4);
  int*   csr   = (int*)alloc((size_t)ET * 4);
  float* dinv  = (float*)alloc((size_t)N * 4);
  u16*   gb    = (u16*)alloc((size_t)B * 1568 * 2);
  int*   bsum  = (int*)alloc((size_t)64 * 4);

  u16*   xb    = (u16*)buf1;
  u16*   Ind   = (u16*)((char*)buf1 + (size_t)N * 96 * 2);
  u16*   x1b   = (u16*)buf1;
  u16*   hb    = (u16*)buf0;
  float* g1f = buf0;
  float* xtf = g1f + (size_t)1024 * 1500;
  float* g2f = xtf + (size_t)1024 * 128;
  float* z1f = g2f + (size_t)1024 * 128;
  float* z2f = z1f + (size_t)1024 * 1024;
  size_t skBytes = ((size_t)1024 * (1500 + 128 + 128 + 1024 + 512)) * 4;
  u16* g1b = (u16*)buf1;
  u16* xcb = g1b + (size_t)1024 * 1504;
  u16* z1b = xcb + (size_t)1024 * 256;
  u16* z2b = z1b + (size_t)1024 * 1024;

  hipMemsetAsync(cnt, 0, (size_t)N * 4, stream);
  hipMemsetAsync(fillp, 0, (size_t)N * 4, stream);

  int nbx = (N * 96 + 255) / 256;
  int nprep = nbx + 84 + 700 + 2352 + 188 + 484 + 256 + 512 + 1024 + 20 + 1024 + (ET + 255) / 256;
  prep_all<<<nprep, 256, 0, stream>>>(
      x, xb, gat_W, wt1, gcn_W, wt2, fcg1_W, wtg1, fcg2_W, wtg2,
      fc1xt_W, wtxt, fc1_W, wtf1, fc2_W, wtf2, convW, wtc,
      att_src, att_dst, tgt, Ind, ei, cnt, N, E);

  int nb1 = 7 * (N / 128);
  int nb2 = 2 * (26624 / 128);
  gemm_dual<<<nb1 + nb2, 256, 0, stream>>>(
      xb, wt1, hb, att, HID, 96, 800, 7, nb1,
      Ind, wtc, Ab, 256, 1024, 256, 2);

  int nblk = (N + 1023) / 1024;
  scan1<<<nblk, 1024, 0, stream>>>(cnt, offs, dinv, bsum, N);
  scan2<<<nblk, 1024, 0, stream>>>(offs, bsum, N, nblk);
  conv_xt<<<B, 256, 0, stream>>>(Ab, embed, convb, convflat);
  fill_csr<<<(ET + 255) / 256, 256, 0, stream>>>(ei, E, N, offs, fillp, csr);

  gat_gather<<<N, 64, 0, stream>>>(hb, att, offs, csr, gat_bias, x1b);

  gemm_mfma<<<dim3(7, N / 128), 256, 0, stream>>>(x1b, wt2, hb, nullptr, HID, 800, 800);

  gcn_pool<<<B, 256, 0, stream>>>(hb, offs, csr, dinv, gcn_bias, batch, N, gb);

  hipMemsetAsync(g1f, 0, skBytes, stream);

  gemm_sk_dual<<<128 + 192, 256, 0, stream>>>(
      convflat, wtxt, xtf, 128, 3872, 256, 1, 8, 128,
      gb, wtg1, g1f, 1500, 1568, 800, 12, 8);
  int nbias = (B * 128 + B * 1504 + 255) / 256;
  bias_dual<<<nbias, 256, 0, stream>>>(
      xtf, fc1xt_b, xcb + 128, B, 128, 128, 256,
      g1f, fcg1_b, g1b, B, 1500, 1504, 1504);

  gemm_sk<<<dim3(1, B / 128, 8), 256, 0, stream>>>(g1b, wtg2, g2f, 128, 1504, 192);
  bias_act_pad<false><<<(B * 128 + 255) / 256, 256, 0, stream>>>(
      g2f, fcg2_b, xcb, B, 128, 128, 256);

  gemm_sk<<<dim3(8, B / 128, 2), 256, 0, stream>>>(xcb, wtf1, z1f, 1024, 256, 128);
  bias_act_pad<true><<<(B * 1024 + 255) / 256, 256, 0, stream>>>(
      z1f, fc1_b, z1b, B, 1024, 1024, 1024);

  gemm_sk<<<dim3(4, B / 128, 4), 256, 0, stream>>>(z1b, wtf2, z2f, 512, 1024, 256);
  bias_act_pad<true><<<(B * 512 + 255) / 256, 256, 0, stream>>>(
      z2f, fc2_b, z2b, B, 512, 512, 512);

  final_out<<<B / 4, 256, 0, stream>>>(z2b, out_W, out_b, (float*)d_out);
}